// Round 5
// baseline (97.541 us; speedup 1.0000x reference)
//
#include <hip/hip_runtime.h>
#include <math.h>

#pragma clang fp contract(off)

#define NUM_PRIORS 72192
#define BATCH      64
#define TOPK       200
#define CONF_TH    0.01f
#define NMS_TH     0.45f
#define NBINS      256
#define SLICES     32
#define ROWS       (NUM_PRIORS / SLICES)   // 2256
#define Q4         (ROWS / 2)              // 1128 float4 per slice
#define CAPS       64                      // candidate slots per slice segment
#define CAP        1024                    // max merged candidates per batch
#define SUPW       7                       // ceil(200/32)

typedef unsigned long long u64;

// ---- binning: monotonic map score -> bin, identical everywhere ----
__device__ __forceinline__ int bin_of(float s) {
    int b = (int)(s * 256.0f);
    return b > 255 ? 255 : b;
}

// ---------------- kernel 1: per-(batch,slice) histogram, plain stores ----------------
__global__ __launch_bounds__(256) void hist_kernel(const float* __restrict__ conf,
                                                   unsigned short* __restrict__ shist) {
    __shared__ unsigned lhist[NBINS];
    const int b = blockIdx.y, slice = blockIdx.x, tid = threadIdx.x;
    lhist[tid] = 0;
    __syncthreads();
    const float4* c4 = (const float4*)conf;
    const long base4 = (long)b * (NUM_PRIORS / 2) + (long)slice * Q4;
    float4 v0 = c4[base4 + tid];
    float4 v1 = c4[base4 + tid + 256];
    float4 v2 = c4[base4 + tid + 512];
    float4 v3 = c4[base4 + tid + 768];
    if (v0.y > CONF_TH) atomicAdd(&lhist[bin_of(v0.y)], 1u);
    if (v0.w > CONF_TH) atomicAdd(&lhist[bin_of(v0.w)], 1u);
    if (v1.y > CONF_TH) atomicAdd(&lhist[bin_of(v1.y)], 1u);
    if (v1.w > CONF_TH) atomicAdd(&lhist[bin_of(v1.w)], 1u);
    if (v2.y > CONF_TH) atomicAdd(&lhist[bin_of(v2.y)], 1u);
    if (v2.w > CONF_TH) atomicAdd(&lhist[bin_of(v2.w)], 1u);
    if (v3.y > CONF_TH) atomicAdd(&lhist[bin_of(v3.y)], 1u);
    if (v3.w > CONF_TH) atomicAdd(&lhist[bin_of(v3.w)], 1u);
    if (tid < Q4 - 1024) {
        float4 vt = c4[base4 + tid + 1024];
        if (vt.y > CONF_TH) atomicAdd(&lhist[bin_of(vt.y)], 1u);
        if (vt.w > CONF_TH) atomicAdd(&lhist[bin_of(vt.w)], 1u);
    }
    __syncthreads();
    shist[((long)b * SLICES + slice) * NBINS + tid] = (unsigned short)lhist[tid];
}

// ---------------- kernel 2: per-batch threshold bin ----------------
__global__ __launch_bounds__(256) void thresh_kernel(const unsigned short* __restrict__ shist,
                                                     unsigned* __restrict__ Tarr) {
    __shared__ unsigned suf[NBINS];
    __shared__ int Tsh;
    const int b = blockIdx.x, tid = threadIdx.x;
    unsigned acc = 0;
    const unsigned short* hb = shist + (long)b * SLICES * NBINS;
#pragma unroll
    for (int s = 0; s < SLICES; s++) acc += (unsigned)hb[s * NBINS + tid];
    suf[tid] = acc;
    if (tid == 0) Tsh = 0;
    __syncthreads();
    for (int off = 1; off < NBINS; off <<= 1) {
        unsigned v = (tid + off < NBINS) ? suf[tid + off] : 0u;
        __syncthreads();
        suf[tid] += v;
        __syncthreads();
    }
    unsigned s0 = suf[tid];
    unsigned sn = (tid + 1 < NBINS) ? suf[tid + 1] : 0u;
    if (s0 >= TOPK && (tid == NBINS - 1 || sn < TOPK)) Tsh = tid;
    __syncthreads();
    if (tid == 0) Tarr[b] = (unsigned)Tsh;
}

// ---------------- kernel 3: collect survivors into private slice segments ----------------
__global__ __launch_bounds__(256) void collect_kernel(const float* __restrict__ conf,
                                                      const unsigned* __restrict__ Tarr,
                                                      unsigned* __restrict__ scnt,
                                                      u64* __restrict__ cand) {
    __shared__ unsigned lcnt;
    const int b = blockIdx.y, slice = blockIdx.x, tid = threadIdx.x;
    if (tid == 0) lcnt = 0;
    __syncthreads();
    const int T = (int)Tarr[b];
    const float4* c4 = (const float4*)conf;
    const long base4 = (long)b * (NUM_PRIORS / 2) + (long)slice * Q4;
    const int prow0 = slice * ROWS;
    u64* seg = cand + ((long)b * SLICES + slice) * CAPS;

    float4 v0 = c4[base4 + tid];
    float4 v1 = c4[base4 + tid + 256];
    float4 v2 = c4[base4 + tid + 512];
    float4 v3 = c4[base4 + tid + 768];

#define SLOT(sv, pidx)                                                          \
    do {                                                                        \
        float s_ = (sv);                                                        \
        if (s_ > CONF_TH && bin_of(s_) >= T) {                                  \
            unsigned pos = atomicAdd(&lcnt, 1u);                                \
            if (pos < CAPS)                                                     \
                seg[pos] = ((u64)__float_as_uint(s_) << 32) |                   \
                           (u64)(0xFFFFFFFFu - (unsigned)(pidx));               \
        }                                                                       \
    } while (0)

    SLOT(v0.y, prow0 + 2 * tid);
    SLOT(v0.w, prow0 + 2 * tid + 1);
    SLOT(v1.y, prow0 + 2 * (tid + 256));
    SLOT(v1.w, prow0 + 2 * (tid + 256) + 1);
    SLOT(v2.y, prow0 + 2 * (tid + 512));
    SLOT(v2.w, prow0 + 2 * (tid + 512) + 1);
    SLOT(v3.y, prow0 + 2 * (tid + 768));
    SLOT(v3.w, prow0 + 2 * (tid + 768) + 1);
    if (tid < Q4 - 1024) {
        float4 vt = c4[base4 + tid + 1024];
        SLOT(vt.y, prow0 + 2 * (tid + 1024));
        SLOT(vt.w, prow0 + 2 * (tid + 1024) + 1);
    }
#undef SLOT
    __syncthreads();
    if (tid == 0) {
        unsigned c = lcnt;
        scnt[b * SLICES + slice] = (c < CAPS) ? c : CAPS;
    }
}

// ---------------- kernel 4: merge slice segments -> gkeys[b], zero out/dbox ----------------
__global__ __launch_bounds__(256) void merge_kernel(const unsigned* __restrict__ scnt,
                                                    const u64* __restrict__ cand,
                                                    u64* __restrict__ gkeys,
                                                    unsigned* __restrict__ nB,
                                                    float4* __restrict__ dbox,
                                                    float* __restrict__ out) {
    __shared__ int soff[SLICES + 1];
    __shared__ int scl[SLICES];
    const int b = blockIdx.x, tid = threadIdx.x;

    if (tid < 64) {
        int s = tid;
        int c = 0;
        if (s < SLICES) {
            unsigned cs = scnt[b * SLICES + s];
            c = (cs < CAPS) ? (int)cs : CAPS;
        }
        int v = c;
#pragma unroll
        for (int d = 1; d < 32; d <<= 1) {
            int o = __shfl_up(v, d);
            if ((int)tid >= d) v += o;
        }
        if (s < SLICES) {
            int P = v - c;
            int off = P > CAP ? CAP : P;
            int rem = CAP - off;
            int cl = c < rem ? c : rem;
            soff[s] = off;
            scl[s] = cl;
            if (s == SLICES - 1) soff[SLICES] = (P + c > CAP) ? CAP : (P + c);
        }
    }
    // zero this batch's output region + decoded-box buffer
    {
        float* ob = out + (long)b * 2 * TOPK * 5;
        for (int i = tid; i < 2 * TOPK * 5; i += 256) ob[i] = 0.f;
        float4 z = make_float4(0.f, 0.f, 0.f, 0.f);
        for (int i = tid; i < TOPK * 2; i += 256) dbox[(long)b * TOPK * 2 + i] = z;
    }
    __syncthreads();
    const int n = soff[SLICES];
    const int nn = (n + 7) & ~7;
    for (int pos = tid; pos < SLICES * CAPS; pos += 256) {
        int s = pos >> 6, idx = pos & 63;
        if (idx < scl[s])
            gkeys[(long)b * CAP + soff[s] + idx] = cand[((long)b * SLICES + s) * CAPS + idx];
    }
    for (int i = n + tid; i < nn; i += 256) gkeys[(long)b * CAP + i] = 0ull;
    if (tid == 0) nB[b] = (unsigned)n;
}

// ---------------- kernel 5: rank (exact top_k order) + decode winners ----------------
__global__ __launch_bounds__(256) void rank_decode_kernel(const float* __restrict__ loc,
                                                          const float* __restrict__ prior,
                                                          const u64* __restrict__ gkeys,
                                                          const unsigned* __restrict__ nB,
                                                          float4* __restrict__ dbox) {
    __shared__ u64 keys[CAP];
    const int b = blockIdx.y, q = blockIdx.x, tid = threadIdx.x;
    const int n = (int)nB[b];
    const int base = q * 512;
    if (base > 0 && base >= n) return;          // uniform across block
    const int nn = (n + 7) & ~7;
    for (int i = tid; i < nn; i += 256) keys[i] = gkeys[(long)b * CAP + i];
    __syncthreads();

    const int c0i = base + tid, c1i = base + 256 + tid;
    u64 kc0 = (c0i < n) ? keys[c0i] : 0ull;
    u64 kc1 = (c1i < n) ? keys[c1i] : 0ull;
    int r0 = 0, r1 = 0;
    for (int k = 0; k < nn; k += 8) {
        u64 kb[8];
#pragma unroll
        for (int j = 0; j < 8; j++) kb[j] = keys[k + j];
#pragma unroll
        for (int j = 0; j < 8; j++) {
            r0 += (kb[j] > kc0) ? 1 : 0;
            r1 += (kb[j] > kc1) ? 1 : 0;
        }
    }
#define DECODE(cidx, key, r)                                                    \
    do {                                                                        \
        if ((cidx) < n && (r) < TOPK) {                                         \
            float sc = __uint_as_float((unsigned)((key) >> 32));                \
            unsigned p = 0xFFFFFFFFu - (unsigned)((key) & 0xFFFFFFFFull);       \
            float4 l4 = ((const float4*)loc)[(long)b * NUM_PRIORS + p];         \
            float4 p4 = ((const float4*)prior)[p];                              \
            float cx = p4.x + (l4.x * 0.1f) * p4.z;                             \
            float cy = p4.y + (l4.y * 0.1f) * p4.w;                             \
            float w_ = p4.z * (float)exp((double)(l4.z * 0.2f));                \
            float h_ = p4.w * (float)exp((double)(l4.w * 0.2f));                \
            float x1 = cx - w_ * 0.5f, y1 = cy - h_ * 0.5f;                     \
            float x2 = cx + w_ * 0.5f, y2 = cy + h_ * 0.5f;                     \
            dbox[((long)b * TOPK + (r)) * 2 + 0] = make_float4(x1, y1, x2, y2); \
            dbox[((long)b * TOPK + (r)) * 2 + 1] =                              \
                make_float4(sc, (x2 - x1) * (y2 - y1), 1.0f, 0.f);              \
        }                                                                       \
    } while (0)
    DECODE(c0i, kc0, r0);
    DECODE(c1i, kc1, r1);
#undef DECODE
}

// ---------------- kernel 6: suppression bitmask + ballot greedy + compact ----------------
__global__ __launch_bounds__(256) void sup_greedy_kernel(const float4* __restrict__ dbox,
                                                         float* __restrict__ out) {
    __shared__ float4 bbox[TOPK];
    __shared__ float bar_s[TOPK], bsc_s[TOPK];
    __shared__ unsigned supT[TOPK][SUPW];
    __shared__ u64 keepw[4];
    __shared__ unsigned char vld[TOPK];
    const int b = blockIdx.x, tid = threadIdx.x;

    if (tid < TOPK) {
        float4 bb = dbox[((long)b * TOPK + tid) * 2 + 0];
        float4 mm = dbox[((long)b * TOPK + tid) * 2 + 1];
        bbox[tid] = bb;
        bsc_s[tid] = mm.x;
        bar_s[tid] = mm.y;
        vld[tid] = (mm.z != 0.f) ? 1 : 0;
    }
    __syncthreads();

    // ---- build column-major suppression bitmask (thread j owns column j) ----
    if (tid < TOPK) {
        const int j = tid;
        const float4 jb = bbox[j];
        const float jar = bar_s[j];
#pragma unroll
        for (int w = 0; w < SUPW; w++) {
            unsigned bits = 0u;
            const int nb = (w == 6) ? 8 : 32;
#pragma unroll
            for (int t = 0; t < nb; t++) {
                const int i = w * 32 + t;
                if (i < j) {
                    float4 ib = bbox[i];
                    float ltx = fmaxf(ib.x, jb.x);
                    float lty = fmaxf(ib.y, jb.y);
                    float rbx = fminf(ib.z, jb.z);
                    float rby = fminf(ib.w, jb.w);
                    float wx = fmaxf(rbx - ltx, 0.0f);
                    float wy = fmaxf(rby - lty, 0.0f);
                    float inter = wx * wy;
                    float uni = (bar_s[i] + jar) - inter;
                    float iou = inter / fmaxf(uni, 1e-12f);
                    if (iou > NMS_TH) bits |= 1u << t;
                }
            }
            supT[j][w] = bits;
        }
    }
    __syncthreads();

    // ---- greedy resolve: wave 0, all-register, ballot-based, fully unrolled ----
    if (tid < 64) {
        const int l = tid;
        unsigned c0[SUPW], c1[SUPW], c2[SUPW], c3[SUPW];
#pragma unroll
        for (int w = 0; w < SUPW; w++) {
            c0[w] = supT[l][w];
            c1[w] = supT[l + 64][w];
            c2[w] = supT[l + 128][w];
            c3[w] = (l < 8) ? supT[l + 192][w] : 0u;
        }
        u64 k0 = __ballot(vld[l] != 0);
        u64 k1 = __ballot(vld[l + 64] != 0);
        u64 k2 = __ballot(vld[l + 128] != 0);
        u64 k3 = __ballot((l < 8) && (vld[l + 192] != 0));
#pragma unroll
        for (int w = 0; w < SUPW; w++) {
            const int nb = (w == 6) ? 8 : 32;
#pragma unroll
            for (int t = 0; t < nb; t++) {
                u64 m0 = __ballot(((c0[w] >> t) & 1u) != 0);
                u64 m1 = __ballot(((c1[w] >> t) & 1u) != 0);
                u64 m2 = __ballot(((c2[w] >> t) & 1u) != 0);
                u64 m3 = __ballot(((c3[w] >> t) & 1u) != 0);
                const int slot = w >> 1;
                u64 kw_ = (slot == 0) ? k0 : (slot == 1) ? k1
                         : (slot == 2) ? k2 : k3;
                bool ki = (kw_ >> ((w & 1) * 32 + t)) & 1ull;   // compile-time shift
                if (ki) { k0 &= ~m0; k1 &= ~m1; k2 &= ~m2; k3 &= ~m3; }
            }
        }
        if (l == 0) { keepw[0] = k0; keepw[1] = k1; keepw[2] = k2; keepw[3] = k3; }
    }
    __syncthreads();

    // ---- compact + write kept rows (out pre-zeroed by merge_kernel) ----
    if (tid < TOPK) {
        const int slot = tid >> 6, off = tid & 63;
        const u64 kw_ = keepw[slot];
        if ((kw_ >> off) & 1ull) {
            int pos = 0;
            for (int s2 = 0; s2 < slot; s2++) pos += __popcll(keepw[s2]);
            pos += __popcll(kw_ & ((1ull << off) - 1ull));
            float4 jb = bbox[tid];
            float* o = out + (((long)b * 2 + 1) * TOPK + pos) * 5;
            o[0] = bsc_s[tid];
            o[1] = jb.x;
            o[2] = jb.y;
            o[3] = jb.z;
            o[4] = jb.w;
        }
    }
}

extern "C" void kernel_launch(void* const* d_in, const int* in_sizes, int n_in,
                              void* d_out, int out_size, void* d_ws, size_t ws_size,
                              hipStream_t stream) {
    const float* loc   = (const float*)d_in[0];   // [64, 72192, 4]
    const float* conf  = (const float*)d_in[1];   // [64*72192, 2]
    const float* prior = (const float*)d_in[2];   // [72192, 4]
    float* out = (float*)d_out;                   // [64, 2, 200, 5]

    // ws layout (all regions fully written every launch -> no memset needed)
    char* w = (char*)d_ws;
    unsigned short* shist = (unsigned short*)w;            // 64*32*256 u16 = 1,048,576
    unsigned* scnt = (unsigned*)(w + 1048576);             // 64*32 u32     =     8,192
    unsigned* Tarr = (unsigned*)(w + 1056768);             // 64 u32        =       256
    unsigned* nB   = (unsigned*)(w + 1057024);             // 64 u32        =       256
    u64* cand      = (u64*)(w + 1057280);                  // 64*32*64 u64  = 1,048,576
    u64* gkeys     = (u64*)(w + 2105856);                  // 64*1024 u64   =   524,288
    float4* dbox   = (float4*)(w + 2630144);               // 64*200*2 f4   =   409,600
                                                           // total 3,039,744 B

    hist_kernel<<<dim3(SLICES, BATCH), 256, 0, stream>>>(conf, shist);
    thresh_kernel<<<BATCH, 256, 0, stream>>>(shist, Tarr);
    collect_kernel<<<dim3(SLICES, BATCH), 256, 0, stream>>>(conf, Tarr, scnt, cand);
    merge_kernel<<<BATCH, 256, 0, stream>>>(scnt, cand, gkeys, nB, dbox, out);
    rank_decode_kernel<<<dim3(2, BATCH), 256, 0, stream>>>(loc, prior, gkeys, nB, dbox);
    sup_greedy_kernel<<<BATCH, 256, 0, stream>>>(dbox, out);
}

// Round 6
// 74.794 us; speedup vs baseline: 1.3041x; 1.3041x over previous
//
#include <hip/hip_runtime.h>
#include <math.h>

#pragma clang fp contract(off)

#define NUM_PRIORS 72192
#define BATCH      64
#define TOPK       200
#define CONF_TH    0.01f
#define NMS_TH     0.45f
#define NBINS      256
#define SLICES     32
#define ROWS       (NUM_PRIORS / SLICES)   // 2256
#define Q4         (ROWS / 2)              // 1128 float4 per slice
#define CAPS       64                      // candidate slots per slice segment
#define CAP        1024                    // max merged candidates per batch
#define KW         7                       // keep-mask words, ceil(200/32)

typedef unsigned long long u64;

// ---- binning: monotonic map score -> bin, identical everywhere ----
__device__ __forceinline__ int bin_of(float s) {
    int b = (int)(s * 256.0f);
    return b > 255 ? 255 : b;
}

// ---------------- kernel 1: per-(batch,slice) histogram, plain stores ----------------
__global__ __launch_bounds__(256) void hist_kernel(const float* __restrict__ conf,
                                                   unsigned short* __restrict__ shist) {
    __shared__ unsigned lhist[NBINS];
    const int b = blockIdx.y, slice = blockIdx.x, tid = threadIdx.x;
    lhist[tid] = 0;
    __syncthreads();
    const float4* c4 = (const float4*)conf;
    const long base4 = (long)b * (NUM_PRIORS / 2) + (long)slice * Q4;
    float4 v0 = c4[base4 + tid];
    float4 v1 = c4[base4 + tid + 256];
    float4 v2 = c4[base4 + tid + 512];
    float4 v3 = c4[base4 + tid + 768];
    if (v0.y > CONF_TH) atomicAdd(&lhist[bin_of(v0.y)], 1u);
    if (v0.w > CONF_TH) atomicAdd(&lhist[bin_of(v0.w)], 1u);
    if (v1.y > CONF_TH) atomicAdd(&lhist[bin_of(v1.y)], 1u);
    if (v1.w > CONF_TH) atomicAdd(&lhist[bin_of(v1.w)], 1u);
    if (v2.y > CONF_TH) atomicAdd(&lhist[bin_of(v2.y)], 1u);
    if (v2.w > CONF_TH) atomicAdd(&lhist[bin_of(v2.w)], 1u);
    if (v3.y > CONF_TH) atomicAdd(&lhist[bin_of(v3.y)], 1u);
    if (v3.w > CONF_TH) atomicAdd(&lhist[bin_of(v3.w)], 1u);
    if (tid < Q4 - 1024) {
        float4 vt = c4[base4 + tid + 1024];
        if (vt.y > CONF_TH) atomicAdd(&lhist[bin_of(vt.y)], 1u);
        if (vt.w > CONF_TH) atomicAdd(&lhist[bin_of(vt.w)], 1u);
    }
    __syncthreads();
    shist[((long)b * SLICES + slice) * NBINS + tid] = (unsigned short)lhist[tid];
}

// ---------------- kernel 2: per-batch threshold bin ----------------
__global__ __launch_bounds__(256) void thresh_kernel(const unsigned short* __restrict__ shist,
                                                     unsigned* __restrict__ Tarr) {
    __shared__ unsigned suf[NBINS];
    __shared__ int Tsh;
    const int b = blockIdx.x, tid = threadIdx.x;
    unsigned acc = 0;
    const unsigned short* hb = shist + (long)b * SLICES * NBINS;
#pragma unroll
    for (int s = 0; s < SLICES; s++) acc += (unsigned)hb[s * NBINS + tid];
    suf[tid] = acc;
    if (tid == 0) Tsh = 0;
    __syncthreads();
    for (int off = 1; off < NBINS; off <<= 1) {
        unsigned v = (tid + off < NBINS) ? suf[tid + off] : 0u;
        __syncthreads();
        suf[tid] += v;
        __syncthreads();
    }
    unsigned s0 = suf[tid];
    unsigned sn = (tid + 1 < NBINS) ? suf[tid + 1] : 0u;
    if (s0 >= TOPK && (tid == NBINS - 1 || sn < TOPK)) Tsh = tid;
    __syncthreads();
    if (tid == 0) Tarr[b] = (unsigned)Tsh;
}

// ---------------- kernel 3: collect survivors into private slice segments ----------------
__global__ __launch_bounds__(256) void collect_kernel(const float* __restrict__ conf,
                                                      const unsigned* __restrict__ Tarr,
                                                      unsigned* __restrict__ scnt,
                                                      u64* __restrict__ cand) {
    __shared__ unsigned lcnt;
    const int b = blockIdx.y, slice = blockIdx.x, tid = threadIdx.x;
    if (tid == 0) lcnt = 0;
    __syncthreads();
    const int T = (int)Tarr[b];
    const float4* c4 = (const float4*)conf;
    const long base4 = (long)b * (NUM_PRIORS / 2) + (long)slice * Q4;
    const int prow0 = slice * ROWS;
    u64* seg = cand + ((long)b * SLICES + slice) * CAPS;

    float4 v0 = c4[base4 + tid];
    float4 v1 = c4[base4 + tid + 256];
    float4 v2 = c4[base4 + tid + 512];
    float4 v3 = c4[base4 + tid + 768];

#define SLOT(sv, pidx)                                                          \
    do {                                                                        \
        float s_ = (sv);                                                        \
        if (s_ > CONF_TH && bin_of(s_) >= T) {                                  \
            unsigned pos = atomicAdd(&lcnt, 1u);                                \
            if (pos < CAPS)                                                     \
                seg[pos] = ((u64)__float_as_uint(s_) << 32) |                   \
                           (u64)(0xFFFFFFFFu - (unsigned)(pidx));               \
        }                                                                       \
    } while (0)

    SLOT(v0.y, prow0 + 2 * tid);
    SLOT(v0.w, prow0 + 2 * tid + 1);
    SLOT(v1.y, prow0 + 2 * (tid + 256));
    SLOT(v1.w, prow0 + 2 * (tid + 256) + 1);
    SLOT(v2.y, prow0 + 2 * (tid + 512));
    SLOT(v2.w, prow0 + 2 * (tid + 512) + 1);
    SLOT(v3.y, prow0 + 2 * (tid + 768));
    SLOT(v3.w, prow0 + 2 * (tid + 768) + 1);
    if (tid < Q4 - 1024) {
        float4 vt = c4[base4 + tid + 1024];
        SLOT(vt.y, prow0 + 2 * (tid + 1024));
        SLOT(vt.w, prow0 + 2 * (tid + 1024) + 1);
    }
#undef SLOT
    __syncthreads();
    if (tid == 0) {
        unsigned c = lcnt;
        scnt[b * SLICES + slice] = (c < CAPS) ? c : CAPS;
    }
}

// ------- kernel 4: merge, rank, decode, row-mask NMS, register greedy, compact -------
__global__ __launch_bounds__(256) void nms_kernel(const float* __restrict__ loc,
                           const float* __restrict__ prior,
                           const unsigned* __restrict__ scnt,
                           const u64* __restrict__ cand,
                           float* __restrict__ out) {
    __shared__ u64 keys[CAP];
    __shared__ float4 bbox[TOPK];
    __shared__ float bar_s[TOPK], bsc_s[TOPK];
    __shared__ unsigned invR[TOPK][8];      // row i: ~suppression bits over j (pad=~0)
    __shared__ unsigned kw0[KW + 1];
    __shared__ unsigned char vld[TOPK];
    __shared__ int soff[SLICES + 1];
    __shared__ int scl[SLICES];
    const int b = blockIdx.x, tid = threadIdx.x;

    // wave 0: parallel slice-offset scan (1 coalesced load + shfl scan)
    if (tid < 64) {
        int s = tid;
        int c = 0;
        if (s < SLICES) {
            unsigned cs = scnt[b * SLICES + s];
            c = (cs < CAPS) ? (int)cs : CAPS;
        }
        int v = c;
#pragma unroll
        for (int d = 1; d < 32; d <<= 1) {
            int o = __shfl_up(v, d);
            if ((int)tid >= d) v += o;
        }
        if (s < SLICES) {
            int P = v - c;                         // exclusive prefix (untruncated)
            int off = P > CAP ? CAP : P;
            int rem = CAP - off;
            int cl = c < rem ? c : rem;
            soff[s] = off;
            scl[s] = cl;
            if (s == SLICES - 1) soff[SLICES] = (P + c > CAP) ? CAP : (P + c);
        }
    }
    // zero this batch's output region + LDS box state
    {
        float* ob = out + (long)b * 2 * TOPK * 5;
        for (int i = tid; i < 2 * TOPK * 5; i += 256) ob[i] = 0.f;
    }
    if (tid < TOPK) {
        bsc_s[tid] = 0.f; bar_s[tid] = 0.f; vld[tid] = 0;
        bbox[tid] = make_float4(0.f, 0.f, 0.f, 0.f);
    }
    __syncthreads();

    const int n = soff[SLICES];
    const int nn = (n + 7) & ~7;
    for (int pos = tid; pos < SLICES * CAPS; pos += 256) {
        int s = pos >> 6, idx = pos & 63;
        if (idx < scl[s])
            keys[soff[s] + idx] = cand[((long)b * SLICES + s) * CAPS + idx];
    }
    for (int i = n + tid; i < nn; i += 256) keys[i] = 0ull;   // zero pad for unroll
    __syncthreads();

    // ---- rank computation (exact top_k order: keys unique), 8-deep unrolled ----
    u64 kc[4];
#pragma unroll
    for (int s = 0; s < 4; s++) {
        int c = tid + s * 256;
        kc[s] = (c < n) ? keys[c] : 0ull;
    }
    int rk[4] = {0, 0, 0, 0};
    for (int k = 0; k < nn; k += 8) {
        u64 kb[8];
#pragma unroll
        for (int j = 0; j < 8; j++) kb[j] = keys[k + j];
#pragma unroll
        for (int j = 0; j < 8; j++) {
#pragma unroll
            for (int s = 0; s < 4; s++) rk[s] += (kb[j] > kc[s]) ? 1 : 0;
        }
    }
    // ---- fused decode of winners (identical float expressions to prior rounds) ----
#pragma unroll
    for (int s = 0; s < 4; s++) {
        int c = tid + s * 256;
        int r = rk[s];
        if (c < n && r < TOPK) {
            u64 key = kc[s];
            float sc = __uint_as_float((unsigned)(key >> 32));
            unsigned p = 0xFFFFFFFFu - (unsigned)(key & 0xFFFFFFFFull);
            float4 l4 = ((const float4*)loc)[(long)b * NUM_PRIORS + p];
            float4 p4 = ((const float4*)prior)[p];
            float cx = p4.x + (l4.x * 0.1f) * p4.z;
            float cy = p4.y + (l4.y * 0.1f) * p4.w;
            float w_ = p4.z * (float)exp((double)(l4.z * 0.2f));
            float h_ = p4.w * (float)exp((double)(l4.w * 0.2f));
            float x1 = cx - w_ * 0.5f, y1 = cy - h_ * 0.5f;
            float x2 = cx + w_ * 0.5f, y2 = cy + h_ * 0.5f;
            bsc_s[r] = sc;
            bbox[r] = make_float4(x1, y1, x2, y2);
            bar_s[r] = (x2 - x1) * (y2 - y1);
            vld[r] = 1;
        }
    }
    __syncthreads();

    // ---- build inverted row-major suppression mask (thread i owns row i) ----
    if (tid < TOPK) {
        const int i = tid;
        const float4 ib = bbox[i];
        const float iar = bar_s[i];
#pragma unroll
        for (int w = 0; w < KW; w++) {
            unsigned inv = 0xFFFFFFFFu;
            const int nb = (w == 6) ? 8 : 32;
            for (int t = 0; t < nb; t++) {
                const int j = w * 32 + t;
                if (j > i) {
                    float4 jb = bbox[j];            // broadcast ds_read_b128
                    float ltx = fmaxf(ib.x, jb.x);
                    float lty = fmaxf(ib.y, jb.y);
                    float rbx = fminf(ib.z, jb.z);
                    float rby = fminf(ib.w, jb.w);
                    float wx = fmaxf(rbx - ltx, 0.0f);
                    float wy = fmaxf(rby - lty, 0.0f);
                    float inter = wx * wy;
                    float uni = (iar + bar_s[j]) - inter;
                    float iou = inter / fmaxf(uni, 1e-12f);
                    if (iou > NMS_TH) inv &= ~(1u << t);
                }
            }
            invR[i][w] = inv;
        }
        invR[i][7] = 0xFFFFFFFFu;
    }
    // initial keep mask from vld (7 builder threads; word 6 limited to 8 bits)
    if (tid >= 224 && tid < 224 + KW) {
        const int w = tid - 224;
        unsigned bits = 0u;
        const int nb = (w == 6) ? 8 : 32;
        for (int t = 0; t < nb; t++)
            bits |= (vld[w * 32 + t] ? 1u : 0u) << t;
        kw0[w] = bits;
    }
    __syncthreads();

    // ---- greedy resolve: fully unrolled, keep mask in registers, replicated ----
    unsigned kk[KW];
#pragma unroll
    for (int w = 0; w < KW; w++) kk[w] = kw0[w];
#pragma unroll
    for (int i = 0; i < TOPK; i++) {
        uint4 a = *(const uint4*)&invR[i][0];    // static addr, pipelined
        uint4 c = *(const uint4*)&invR[i][4];
        if ((kk[i >> 5] >> (i & 31)) & 1u) {     // compile-time word/shift
            kk[0] &= a.x; kk[1] &= a.y; kk[2] &= a.z; kk[3] &= a.w;
            kk[4] &= c.x; kk[5] &= c.y; kk[6] &= c.z;
        }
    }

    // ---- compact + write kept rows (all threads hold final kk) ----
    if (tid < TOPK) {
        const int wsel = tid >> 5, bsel = tid & 31;
        if ((kk[wsel] >> bsel) & 1u) {
            int pos = 0;
#pragma unroll
            for (int w = 0; w < KW; w++) {
                if (w < wsel) pos += __popc(kk[w]);
                else if (w == wsel) pos += __popc(kk[w] & ((bsel == 0) ? 0u : (0xFFFFFFFFu >> (32 - bsel))));
            }
            float4 jb = bbox[tid];
            float* o = out + (((long)b * 2 + 1) * TOPK + pos) * 5;
            o[0] = bsc_s[tid];
            o[1] = jb.x;
            o[2] = jb.y;
            o[3] = jb.z;
            o[4] = jb.w;
        }
    }
}

extern "C" void kernel_launch(void* const* d_in, const int* in_sizes, int n_in,
                              void* d_out, int out_size, void* d_ws, size_t ws_size,
                              hipStream_t stream) {
    const float* loc   = (const float*)d_in[0];   // [64, 72192, 4]
    const float* conf  = (const float*)d_in[1];   // [64*72192, 2]
    const float* prior = (const float*)d_in[2];   // [72192, 4]
    float* out = (float*)d_out;                   // [64, 2, 200, 5]

    // ws layout (all regions fully written every launch -> no memset needed)
    char* w = (char*)d_ws;
    unsigned short* shist = (unsigned short*)w;            // 64*32*256 u16 = 1,048,576
    unsigned* scnt = (unsigned*)(w + 1048576);             // 64*32 u32     =     8,192
    unsigned* Tarr = (unsigned*)(w + 1056768);             // 64 u32        =       256
    u64* cand      = (u64*)(w + 1057024);                  // 64*32*64 u64  = 1,048,576

    hist_kernel<<<dim3(SLICES, BATCH), 256, 0, stream>>>(conf, shist);
    thresh_kernel<<<BATCH, 256, 0, stream>>>(shist, Tarr);
    collect_kernel<<<dim3(SLICES, BATCH), 256, 0, stream>>>(conf, Tarr, scnt, cand);
    nms_kernel<<<BATCH, 256, 0, stream>>>(loc, prior, scnt, cand, out);
}

// Round 7
// 60.010 us; speedup vs baseline: 1.6254x; 1.2463x over previous
//
#include <hip/hip_runtime.h>
#include <math.h>

#pragma clang fp contract(off)

#define NUM_PRIORS 72192
#define BATCH      64
#define TOPK       200
#define CONF_TH    0.01f
#define NMS_TH     0.45f
#define NBINS      256
#define SLICES     32
#define ROWS       (NUM_PRIORS / SLICES)   // 2256
#define Q4         (ROWS / 2)              // 1128 float4 per slice
#define CAPS       64                      // candidate slots per slice segment
#define CAP        1024                    // max merged candidates per batch
#define KW         7                       // keep-mask words, ceil(200/32)
#define NMS_NTH    1024                    // nms block size (16 waves)

typedef unsigned long long u64;

// ---- binning: monotonic map score -> bin, identical everywhere ----
__device__ __forceinline__ int bin_of(float s) {
    int b = (int)(s * 256.0f);
    return b > 255 ? 255 : b;
}

// ---------------- kernel 1: per-(batch,slice) histogram, per-wave sub-hists ----------------
__global__ __launch_bounds__(256) void hist_kernel(const float* __restrict__ conf,
                                                   unsigned short* __restrict__ shist) {
    __shared__ unsigned lh[4][NBINS];
    const int b = blockIdx.y, slice = blockIdx.x, tid = threadIdx.x;
    const int wv = tid >> 6;
    for (int i = tid; i < 4 * NBINS; i += 256) ((unsigned*)lh)[i] = 0;
    __syncthreads();
    const float4* c4 = (const float4*)conf;
    const long base4 = (long)b * (NUM_PRIORS / 2) + (long)slice * Q4;
    float4 v0 = c4[base4 + tid];
    float4 v1 = c4[base4 + tid + 256];
    float4 v2 = c4[base4 + tid + 512];
    float4 v3 = c4[base4 + tid + 768];
    if (v0.y > CONF_TH) atomicAdd(&lh[wv][bin_of(v0.y)], 1u);
    if (v0.w > CONF_TH) atomicAdd(&lh[wv][bin_of(v0.w)], 1u);
    if (v1.y > CONF_TH) atomicAdd(&lh[wv][bin_of(v1.y)], 1u);
    if (v1.w > CONF_TH) atomicAdd(&lh[wv][bin_of(v1.w)], 1u);
    if (v2.y > CONF_TH) atomicAdd(&lh[wv][bin_of(v2.y)], 1u);
    if (v2.w > CONF_TH) atomicAdd(&lh[wv][bin_of(v2.w)], 1u);
    if (v3.y > CONF_TH) atomicAdd(&lh[wv][bin_of(v3.y)], 1u);
    if (v3.w > CONF_TH) atomicAdd(&lh[wv][bin_of(v3.w)], 1u);
    if (tid < Q4 - 1024) {
        float4 vt = c4[base4 + tid + 1024];
        if (vt.y > CONF_TH) atomicAdd(&lh[wv][bin_of(vt.y)], 1u);
        if (vt.w > CONF_TH) atomicAdd(&lh[wv][bin_of(vt.w)], 1u);
    }
    __syncthreads();
    shist[((long)b * SLICES + slice) * NBINS + tid] =
        (unsigned short)(lh[0][tid] + lh[1][tid] + lh[2][tid] + lh[3][tid]);
}

// ---------------- kernel 2: per-batch threshold bin ----------------
__global__ __launch_bounds__(256) void thresh_kernel(const unsigned short* __restrict__ shist,
                                                     unsigned* __restrict__ Tarr) {
    __shared__ unsigned suf[NBINS];
    __shared__ int Tsh;
    const int b = blockIdx.x, tid = threadIdx.x;
    unsigned acc = 0;
    const unsigned short* hb = shist + (long)b * SLICES * NBINS;
#pragma unroll
    for (int s = 0; s < SLICES; s++) acc += (unsigned)hb[s * NBINS + tid];
    suf[tid] = acc;
    if (tid == 0) Tsh = 0;
    __syncthreads();
    for (int off = 1; off < NBINS; off <<= 1) {
        unsigned v = (tid + off < NBINS) ? suf[tid + off] : 0u;
        __syncthreads();
        suf[tid] += v;
        __syncthreads();
    }
    unsigned s0 = suf[tid];
    unsigned sn = (tid + 1 < NBINS) ? suf[tid + 1] : 0u;
    if (s0 >= TOPK && (tid == NBINS - 1 || sn < TOPK)) Tsh = tid;
    __syncthreads();
    if (tid == 0) Tarr[b] = (unsigned)Tsh;
}

// ---------------- kernel 3: collect survivors into private slice segments ----------------
__global__ __launch_bounds__(256) void collect_kernel(const float* __restrict__ conf,
                                                      const unsigned* __restrict__ Tarr,
                                                      unsigned* __restrict__ scnt,
                                                      u64* __restrict__ cand) {
    __shared__ unsigned lcnt;
    const int b = blockIdx.y, slice = blockIdx.x, tid = threadIdx.x;
    if (tid == 0) lcnt = 0;
    __syncthreads();
    const int T = (int)Tarr[b];
    const float4* c4 = (const float4*)conf;
    const long base4 = (long)b * (NUM_PRIORS / 2) + (long)slice * Q4;
    const int prow0 = slice * ROWS;
    u64* seg = cand + ((long)b * SLICES + slice) * CAPS;

    float4 v0 = c4[base4 + tid];
    float4 v1 = c4[base4 + tid + 256];
    float4 v2 = c4[base4 + tid + 512];
    float4 v3 = c4[base4 + tid + 768];

#define SLOT(sv, pidx)                                                          \
    do {                                                                        \
        float s_ = (sv);                                                        \
        if (s_ > CONF_TH && bin_of(s_) >= T) {                                  \
            unsigned pos = atomicAdd(&lcnt, 1u);                                \
            if (pos < CAPS)                                                     \
                seg[pos] = ((u64)__float_as_uint(s_) << 32) |                   \
                           (u64)(0xFFFFFFFFu - (unsigned)(pidx));               \
        }                                                                       \
    } while (0)

    SLOT(v0.y, prow0 + 2 * tid);
    SLOT(v0.w, prow0 + 2 * tid + 1);
    SLOT(v1.y, prow0 + 2 * (tid + 256));
    SLOT(v1.w, prow0 + 2 * (tid + 256) + 1);
    SLOT(v2.y, prow0 + 2 * (tid + 512));
    SLOT(v2.w, prow0 + 2 * (tid + 512) + 1);
    SLOT(v3.y, prow0 + 2 * (tid + 768));
    SLOT(v3.w, prow0 + 2 * (tid + 768) + 1);
    if (tid < Q4 - 1024) {
        float4 vt = c4[base4 + tid + 1024];
        SLOT(vt.y, prow0 + 2 * (tid + 1024));
        SLOT(vt.w, prow0 + 2 * (tid + 1024) + 1);
    }
#undef SLOT
    __syncthreads();
    if (tid == 0) {
        unsigned c = lcnt;
        scnt[b * SLICES + slice] = (c < CAPS) ? c : CAPS;
    }
}

// ------- kernel 4: merge, rank, decode, batched row-mask NMS, register greedy -------
__global__ __launch_bounds__(NMS_NTH) void nms_kernel(const float* __restrict__ loc,
                           const float* __restrict__ prior,
                           const unsigned* __restrict__ scnt,
                           const u64* __restrict__ cand,
                           float* __restrict__ out) {
    __shared__ u64 keys[CAP];
    __shared__ float4 bbox[224];            // padded so batched loads never go OOB
    __shared__ float bsc_s[TOPK];
    __shared__ unsigned invR[TOPK][8];      // row i: ~suppression bits over j (pad=~0)
    __shared__ unsigned kw0[8];
    __shared__ unsigned char vld[TOPK];
    __shared__ int soff[SLICES + 1];
    __shared__ int scl[SLICES];
    const int b = blockIdx.x, tid = threadIdx.x;

    // wave 0: parallel slice-offset scan (1 coalesced load + shfl scan)
    if (tid < 64) {
        int s = tid;
        int c = 0;
        if (s < SLICES) {
            unsigned cs = scnt[b * SLICES + s];
            c = (cs < CAPS) ? (int)cs : CAPS;
        }
        int v = c;
#pragma unroll
        for (int d = 1; d < 32; d <<= 1) {
            int o = __shfl_up(v, d);
            if ((int)tid >= d) v += o;
        }
        if (s < SLICES) {
            int P = v - c;                         // exclusive prefix (untruncated)
            int off = P > CAP ? CAP : P;
            int rem = CAP - off;
            int cl = c < rem ? c : rem;
            soff[s] = off;
            scl[s] = cl;
            if (s == SLICES - 1) soff[SLICES] = (P + c > CAP) ? CAP : (P + c);
        }
    }
    // zero this batch's output region + LDS box state
    {
        float* ob = out + (long)b * 2 * TOPK * 5;
        for (int i = tid; i < 2 * TOPK * 5; i += NMS_NTH) ob[i] = 0.f;
    }
    if (tid < 224) {
        bbox[tid] = make_float4(0.f, 0.f, 0.f, 0.f);
        if (tid < TOPK) { bsc_s[tid] = 0.f; vld[tid] = 0; }
    }
    __syncthreads();

    const int n = soff[SLICES];
    const int nn = (n + 15) & ~15;
    for (int pos = tid; pos < SLICES * CAPS; pos += NMS_NTH) {
        int s = pos >> 6, idx = pos & 63;
        if (idx < scl[s])
            keys[soff[s] + idx] = cand[((long)b * SLICES + s) * CAPS + idx];
    }
    for (int i = n + tid; i < nn; i += NMS_NTH) keys[i] = 0ull;   // zero pad
    __syncthreads();

    // ---- rank (exact top_k order: keys unique), 16 reads in flight ----
    u64 kc = (tid < n) ? keys[tid] : 0ull;
    int rk = 0;
    for (int k = 0; k < nn; k += 16) {
        u64 kb[16];
#pragma unroll
        for (int j = 0; j < 16; j++) kb[j] = keys[k + j];
#pragma unroll
        for (int j = 0; j < 16; j++) rk += (kb[j] > kc) ? 1 : 0;
    }
    // ---- fused decode of winners (identical float expressions to prior rounds) ----
    if (tid < n && rk < TOPK) {
        u64 key = kc;
        float sc = __uint_as_float((unsigned)(key >> 32));
        unsigned p = 0xFFFFFFFFu - (unsigned)(key & 0xFFFFFFFFull);
        float4 l4 = ((const float4*)loc)[(long)b * NUM_PRIORS + p];
        float4 p4 = ((const float4*)prior)[p];
        float cx = p4.x + (l4.x * 0.1f) * p4.z;
        float cy = p4.y + (l4.y * 0.1f) * p4.w;
        float w_ = p4.z * (float)exp((double)(l4.z * 0.2f));
        float h_ = p4.w * (float)exp((double)(l4.w * 0.2f));
        float x1 = cx - w_ * 0.5f, y1 = cy - h_ * 0.5f;
        float x2 = cx + w_ * 0.5f, y2 = cy + h_ * 0.5f;
        bsc_s[rk] = sc;
        bbox[rk] = make_float4(x1, y1, x2, y2);
        vld[rk] = 1;
    }
    __syncthreads();

    // ---- build inverted row-major suppression mask, 4-way split + batched loads ----
    // thread 256*q + i owns row i, words {q, q+4} (q==3: word 3 only)
    {
        const int q = tid >> 8, i = tid & 255;
        if (i < TOPK) {
            const float4 ib = bbox[i];
            const float iar = (ib.z - ib.x) * (ib.w - ib.y);   // same expr as reference
#pragma unroll
            for (int wi = 0; wi < 2; wi++) {
                if (wi == 1 && q == 3) break;
                const int w = (wi == 0) ? q : q + 4;
                const int jbase = w * 32;
                unsigned inv = 0xFFFFFFFFu;
#pragma unroll
                for (int g = 0; g < 32; g += 8) {
                    float4 J[8];
#pragma unroll
                    for (int r = 0; r < 8; r++) J[r] = bbox[jbase + g + r];  // broadcast, batched
#pragma unroll
                    for (int r = 0; r < 8; r++) {
                        const int j = jbase + g + r;
                        if (j > i && j < TOPK) {
                            float4 jb = J[r];
                            float jar = (jb.z - jb.x) * (jb.w - jb.y);
                            float ltx = fmaxf(ib.x, jb.x);
                            float lty = fmaxf(ib.y, jb.y);
                            float rbx = fminf(ib.z, jb.z);
                            float rby = fminf(ib.w, jb.w);
                            float wx = fmaxf(rbx - ltx, 0.0f);
                            float wy = fmaxf(rby - lty, 0.0f);
                            float inter = wx * wy;
                            float uni = (iar + jar) - inter;
                            float iou = inter / fmaxf(uni, 1e-12f);
                            if (iou > NMS_TH) inv &= ~(1u << (g + r));
                        }
                    }
                }
                invR[i][w] = inv;
            }
            if (q == 0) invR[i][7] = 0xFFFFFFFFu;
        }
    }
    // initial keep mask from vld (7 builder threads; word 6 limited to 8 bits)
    if (tid >= 224 && tid < 224 + KW) {
        const int w = tid - 224;
        unsigned bits = 0u;
        const int nb = (w == 6) ? 8 : 32;
        for (int t = 0; t < nb; t++)
            bits |= (vld[w * 32 + t] ? 1u : 0u) << t;
        kw0[w] = bits;
    }
    __syncthreads();

    // ---- greedy resolve: replicated register keep-mask, 8 rows (16 b128 loads) per group ----
    unsigned kk[KW];
#pragma unroll
    for (int w = 0; w < KW; w++) kk[w] = kw0[w];
#pragma unroll
    for (int g = 0; g < TOPK; g += 8) {
        uint4 A[8], C[8];
#pragma unroll
        for (int r = 0; r < 8; r++) {
            A[r] = *(const uint4*)&invR[g + r][0];
            C[r] = *(const uint4*)&invR[g + r][4];
        }
#pragma unroll
        for (int r = 0; r < 8; r++) {
            const int i = g + r;                     // compile-time
            if ((kk[i >> 5] >> (i & 31)) & 1u) {
                kk[0] &= A[r].x; kk[1] &= A[r].y; kk[2] &= A[r].z; kk[3] &= A[r].w;
                kk[4] &= C[r].x; kk[5] &= C[r].y; kk[6] &= C[r].z;
            }
        }
    }

    // ---- compact + write kept rows (all threads hold final kk) ----
    if (tid < TOPK) {
        const int wsel = tid >> 5, bsel = tid & 31;
        if ((kk[wsel] >> bsel) & 1u) {
            int pos = 0;
#pragma unroll
            for (int w = 0; w < KW; w++) {
                if (w < wsel) pos += __popc(kk[w]);
                else if (w == wsel) pos += __popc(kk[w] & ((bsel == 0) ? 0u : (0xFFFFFFFFu >> (32 - bsel))));
            }
            float4 jb = bbox[tid];
            float* o = out + (((long)b * 2 + 1) * TOPK + pos) * 5;
            o[0] = bsc_s[tid];
            o[1] = jb.x;
            o[2] = jb.y;
            o[3] = jb.z;
            o[4] = jb.w;
        }
    }
}

extern "C" void kernel_launch(void* const* d_in, const int* in_sizes, int n_in,
                              void* d_out, int out_size, void* d_ws, size_t ws_size,
                              hipStream_t stream) {
    const float* loc   = (const float*)d_in[0];   // [64, 72192, 4]
    const float* conf  = (const float*)d_in[1];   // [64*72192, 2]
    const float* prior = (const float*)d_in[2];   // [72192, 4]
    float* out = (float*)d_out;                   // [64, 2, 200, 5]

    // ws layout (all regions fully written every launch -> no memset needed)
    char* w = (char*)d_ws;
    unsigned short* shist = (unsigned short*)w;            // 64*32*256 u16 = 1,048,576
    unsigned* scnt = (unsigned*)(w + 1048576);             // 64*32 u32     =     8,192
    unsigned* Tarr = (unsigned*)(w + 1056768);             // 64 u32        =       256
    u64* cand      = (u64*)(w + 1057024);                  // 64*32*64 u64  = 1,048,576

    hist_kernel<<<dim3(SLICES, BATCH), 256, 0, stream>>>(conf, shist);
    thresh_kernel<<<BATCH, 256, 0, stream>>>(shist, Tarr);
    collect_kernel<<<dim3(SLICES, BATCH), 256, 0, stream>>>(conf, Tarr, scnt, cand);
    nms_kernel<<<BATCH, NMS_NTH, 0, stream>>>(loc, prior, scnt, cand, out);
}

// Round 8
// 41.451 us; speedup vs baseline: 2.3532x; 1.4478x over previous
//
#include <hip/hip_runtime.h>
#include <math.h>

#pragma clang fp contract(off)

#define NUM_PRIORS 72192
#define BATCH      64
#define TOPK       200
#define CONF_TH    0.01f
#define NMS_TH     0.45f
#define NBINS      256
#define SLICES     32
#define ROWS       (NUM_PRIORS / SLICES)   // 2256
#define Q4         (ROWS / 2)              // 1128 float4 per slice
#define CAPS       64                      // candidate slots per slice segment
#define CAP        1024                    // max merged candidates per batch
#define KW         7                       // keep-mask words, ceil(200/32)
#define NMS_NTH    1024                    // nms block size (16 waves)

typedef unsigned long long u64;

// ---- binning: monotonic map score -> bin, identical everywhere ----
__device__ __forceinline__ int bin_of(float s) {
    int b = (int)(s * 256.0f);
    return b > 255 ? 255 : b;
}

// ---- kernel 1: histogram + optimistic collect of bin-255 candidates (single conf pass) ----
__global__ __launch_bounds__(256) void histcollect_kernel(const float* __restrict__ conf,
                                                          unsigned short* __restrict__ shist,
                                                          unsigned* __restrict__ scnt,
                                                          u64* __restrict__ cand) {
    __shared__ unsigned lh[4][NBINS];
    __shared__ unsigned lcnt;
    const int b = blockIdx.y, slice = blockIdx.x, tid = threadIdx.x;
    const int wv = tid >> 6;
    for (int i = tid; i < 4 * NBINS; i += 256) ((unsigned*)lh)[i] = 0;
    if (tid == 0) lcnt = 0;
    __syncthreads();
    const float4* c4 = (const float4*)conf;
    const long base4 = (long)b * (NUM_PRIORS / 2) + (long)slice * Q4;
    const int prow0 = slice * ROWS;
    u64* seg = cand + ((long)b * SLICES + slice) * CAPS;

    float4 v0 = c4[base4 + tid];
    float4 v1 = c4[base4 + tid + 256];
    float4 v2 = c4[base4 + tid + 512];
    float4 v3 = c4[base4 + tid + 768];

#define PROC(sv, pidx)                                                          \
    do {                                                                        \
        float s_ = (sv);                                                        \
        if (s_ > CONF_TH) {                                                     \
            int bn = bin_of(s_);                                                \
            atomicAdd(&lh[wv][bn], 1u);                                         \
            if (bn == 255) {                                                    \
                unsigned pos = atomicAdd(&lcnt, 1u);                            \
                if (pos < CAPS)                                                 \
                    seg[pos] = ((u64)__float_as_uint(s_) << 32) |               \
                               (u64)(0xFFFFFFFFu - (unsigned)(pidx));           \
            }                                                                   \
        }                                                                       \
    } while (0)

    PROC(v0.y, prow0 + 2 * tid);
    PROC(v0.w, prow0 + 2 * tid + 1);
    PROC(v1.y, prow0 + 2 * (tid + 256));
    PROC(v1.w, prow0 + 2 * (tid + 256) + 1);
    PROC(v2.y, prow0 + 2 * (tid + 512));
    PROC(v2.w, prow0 + 2 * (tid + 512) + 1);
    PROC(v3.y, prow0 + 2 * (tid + 768));
    PROC(v3.w, prow0 + 2 * (tid + 768) + 1);
    if (tid < Q4 - 1024) {
        float4 vt = c4[base4 + tid + 1024];
        PROC(vt.y, prow0 + 2 * (tid + 1024));
        PROC(vt.w, prow0 + 2 * (tid + 1024) + 1);
    }
#undef PROC
    __syncthreads();
    shist[((long)b * SLICES + slice) * NBINS + tid] =
        (unsigned short)(lh[0][tid] + lh[1][tid] + lh[2][tid] + lh[3][tid]);
    if (tid == 0) {
        unsigned c = lcnt;
        scnt[b * SLICES + slice] = (c < CAPS) ? c : CAPS;
    }
}

// ---- kernel 2: threshold; if T != 255 (never on this data) re-collect exactly ----
__global__ __launch_bounds__(256) void fixup_kernel(const float* __restrict__ conf,
                                                    const unsigned short* __restrict__ shist,
                                                    unsigned* __restrict__ scnt,
                                                    u64* __restrict__ cand) {
    __shared__ unsigned suf[NBINS];
    __shared__ int Tsh;
    __shared__ unsigned lcnt;
    const int b = blockIdx.x, tid = threadIdx.x;
    unsigned acc = 0;
    const unsigned short* hb = shist + (long)b * SLICES * NBINS;
#pragma unroll
    for (int s = 0; s < SLICES; s++) acc += (unsigned)hb[s * NBINS + tid];
    suf[tid] = acc;
    if (tid == 0) Tsh = 0;
    __syncthreads();
    for (int off = 1; off < NBINS; off <<= 1) {
        unsigned v = (tid + off < NBINS) ? suf[tid + off] : 0u;
        __syncthreads();
        suf[tid] += v;
        __syncthreads();
    }
    unsigned s0 = suf[tid];
    unsigned sn = (tid + 1 < NBINS) ? suf[tid + 1] : 0u;
    if (s0 >= TOPK && (tid == NBINS - 1 || sn < TOPK)) Tsh = tid;
    __syncthreads();
    const int T = Tsh;
    if (T == 255) return;                 // optimistic collect was exact (hot path)

    // cold correctness path: exact re-collect of this batch with true T
    const float4* c4 = (const float4*)conf;
    for (int s = 0; s < SLICES; s++) {
        __syncthreads();
        if (tid == 0) lcnt = 0;
        __syncthreads();
        const long base4 = (long)b * (NUM_PRIORS / 2) + (long)s * Q4;
        const int prow0 = s * ROWS;
        u64* seg = cand + ((long)b * SLICES + s) * CAPS;
        for (int q = tid; q < Q4; q += 256) {
            float4 v = c4[base4 + q];
            float sy = v.y, sw = v.w;
            if (sy > CONF_TH && bin_of(sy) >= T) {
                unsigned pos = atomicAdd(&lcnt, 1u);
                if (pos < CAPS)
                    seg[pos] = ((u64)__float_as_uint(sy) << 32) |
                               (u64)(0xFFFFFFFFu - (unsigned)(prow0 + 2 * q));
            }
            if (sw > CONF_TH && bin_of(sw) >= T) {
                unsigned pos = atomicAdd(&lcnt, 1u);
                if (pos < CAPS)
                    seg[pos] = ((u64)__float_as_uint(sw) << 32) |
                               (u64)(0xFFFFFFFFu - (unsigned)(prow0 + 2 * q + 1));
            }
        }
        __syncthreads();
        if (tid == 0) {
            unsigned c = lcnt;
            scnt[b * SLICES + s] = (c < CAPS) ? c : CAPS;
        }
    }
}

// ------- kernel 3: merge, rank, decode, row-mask NMS, wave0 greedy, compact -------
__global__ __launch_bounds__(NMS_NTH) void nms_kernel(const float* __restrict__ loc,
                           const float* __restrict__ prior,
                           const unsigned* __restrict__ scnt,
                           const u64* __restrict__ cand,
                           float* __restrict__ out) {
    __shared__ u64 keys[CAP];
    __shared__ float4 bbox[224];            // padded so batched loads never go OOB
    __shared__ float bsc_s[TOPK];
    __shared__ unsigned invR[TOPK][8];      // row i: ~suppression bits over j (pad=~0)
    __shared__ unsigned kw0[8];
    __shared__ unsigned kwF[KW];            // final keep mask (published by wave 0)
    __shared__ unsigned char vld[TOPK];
    __shared__ int soff[SLICES + 1];
    __shared__ int scl[SLICES];
    const int b = blockIdx.x, tid = threadIdx.x;

    // wave 0: parallel slice-offset scan (1 coalesced load + shfl scan)
    if (tid < 64) {
        int s = tid;
        int c = 0;
        if (s < SLICES) {
            unsigned cs = scnt[b * SLICES + s];
            c = (cs < CAPS) ? (int)cs : CAPS;
        }
        int v = c;
#pragma unroll
        for (int d = 1; d < 32; d <<= 1) {
            int o = __shfl_up(v, d);
            if ((int)tid >= d) v += o;
        }
        if (s < SLICES) {
            int P = v - c;                         // exclusive prefix (untruncated)
            int off = P > CAP ? CAP : P;
            int rem = CAP - off;
            int cl = c < rem ? c : rem;
            soff[s] = off;
            scl[s] = cl;
            if (s == SLICES - 1) soff[SLICES] = (P + c > CAP) ? CAP : (P + c);
        }
    }
    // zero this batch's output region + LDS box state
    {
        float* ob = out + (long)b * 2 * TOPK * 5;
        for (int i = tid; i < 2 * TOPK * 5; i += NMS_NTH) ob[i] = 0.f;
    }
    if (tid < 224) {
        bbox[tid] = make_float4(0.f, 0.f, 0.f, 0.f);
        if (tid < TOPK) { bsc_s[tid] = 0.f; vld[tid] = 0; }
    }
    __syncthreads();

    const int n = soff[SLICES];
    const int nn = (n + 15) & ~15;
    for (int pos = tid; pos < SLICES * CAPS; pos += NMS_NTH) {
        int s = pos >> 6, idx = pos & 63;
        if (idx < scl[s])
            keys[soff[s] + idx] = cand[((long)b * SLICES + s) * CAPS + idx];
    }
    for (int i = n + tid; i < nn; i += NMS_NTH) keys[i] = 0ull;   // zero pad
    __syncthreads();

    // ---- rank (exact top_k order: keys unique); only waves holding candidates run ----
    u64 kc = (tid < n) ? keys[tid] : 0ull;
    int rk = 0;
    if ((int)(tid & ~63u) < n) {                  // wave-uniform guard
        for (int k = 0; k < nn; k += 16) {
            u64 kb[16];
#pragma unroll
            for (int j = 0; j < 16; j++) kb[j] = keys[k + j];
#pragma unroll
            for (int j = 0; j < 16; j++) rk += (kb[j] > kc) ? 1 : 0;
        }
    }
    // ---- fused decode of winners (identical float expressions to prior rounds) ----
    if (tid < n && rk < TOPK) {
        u64 key = kc;
        float sc = __uint_as_float((unsigned)(key >> 32));
        unsigned p = 0xFFFFFFFFu - (unsigned)(key & 0xFFFFFFFFull);
        float4 l4 = ((const float4*)loc)[(long)b * NUM_PRIORS + p];
        float4 p4 = ((const float4*)prior)[p];
        float cx = p4.x + (l4.x * 0.1f) * p4.z;
        float cy = p4.y + (l4.y * 0.1f) * p4.w;
        float w_ = p4.z * (float)exp((double)(l4.z * 0.2f));
        float h_ = p4.w * (float)exp((double)(l4.w * 0.2f));
        float x1 = cx - w_ * 0.5f, y1 = cy - h_ * 0.5f;
        float x2 = cx + w_ * 0.5f, y2 = cy + h_ * 0.5f;
        bsc_s[rk] = sc;
        bbox[rk] = make_float4(x1, y1, x2, y2);
        vld[rk] = 1;
    }
    __syncthreads();

    // ---- build inverted row-major suppression mask, 4-way split + batched loads ----
    // thread 256*q + i owns row i, words {q, q+4} (q==3: word 3 only)
    {
        const int q = tid >> 8, i = tid & 255;
        if (i < TOPK) {
            const float4 ib = bbox[i];
            const float iar = (ib.z - ib.x) * (ib.w - ib.y);   // same expr as reference
#pragma unroll
            for (int wi = 0; wi < 2; wi++) {
                if (wi == 1 && q == 3) break;
                const int w = (wi == 0) ? q : q + 4;
                const int jbase = w * 32;
                unsigned inv = 0xFFFFFFFFu;
#pragma unroll
                for (int g = 0; g < 32; g += 8) {
                    float4 J[8];
#pragma unroll
                    for (int r = 0; r < 8; r++) J[r] = bbox[jbase + g + r];  // broadcast, batched
#pragma unroll
                    for (int r = 0; r < 8; r++) {
                        const int j = jbase + g + r;
                        if (j > i && j < TOPK) {
                            float4 jb = J[r];
                            float jar = (jb.z - jb.x) * (jb.w - jb.y);
                            float ltx = fmaxf(ib.x, jb.x);
                            float lty = fmaxf(ib.y, jb.y);
                            float rbx = fminf(ib.z, jb.z);
                            float rby = fminf(ib.w, jb.w);
                            float wx = fmaxf(rbx - ltx, 0.0f);
                            float wy = fmaxf(rby - lty, 0.0f);
                            float inter = wx * wy;
                            float uni = (iar + jar) - inter;
                            float iou = inter / fmaxf(uni, 1e-12f);
                            if (iou > NMS_TH) inv &= ~(1u << (g + r));
                        }
                    }
                }
                invR[i][w] = inv;
            }
            if (q == 0) invR[i][7] = 0xFFFFFFFFu;
        }
    }
    // initial keep mask from vld (7 builder threads; word 6 limited to 8 bits)
    if (tid >= 224 && tid < 224 + KW) {
        const int w = tid - 224;
        unsigned bits = 0u;
        const int nb = (w == 6) ? 8 : 32;
        for (int t = 0; t < nb; t++)
            bits |= (vld[w * 32 + t] ? 1u : 0u) << t;
        kw0[w] = bits;
    }
    __syncthreads();

    // ---- greedy resolve: wave 0 only, register keep-mask, 8 rows per group ----
    if (tid < 64) {
        unsigned kk[KW];
#pragma unroll
        for (int w = 0; w < KW; w++) kk[w] = kw0[w];
#pragma unroll
        for (int g = 0; g < TOPK; g += 8) {
            uint4 A[8], C[8];
#pragma unroll
            for (int r = 0; r < 8; r++) {
                A[r] = *(const uint4*)&invR[g + r][0];
                C[r] = *(const uint4*)&invR[g + r][4];
            }
#pragma unroll
            for (int r = 0; r < 8; r++) {
                const int i = g + r;                     // compile-time
                if ((kk[i >> 5] >> (i & 31)) & 1u) {
                    kk[0] &= A[r].x; kk[1] &= A[r].y; kk[2] &= A[r].z; kk[3] &= A[r].w;
                    kk[4] &= C[r].x; kk[5] &= C[r].y; kk[6] &= C[r].z;
                }
            }
        }
        if (tid == 0) {                                  // static indices (no scratch)
            kwF[0] = kk[0]; kwF[1] = kk[1]; kwF[2] = kk[2]; kwF[3] = kk[3];
            kwF[4] = kk[4]; kwF[5] = kk[5]; kwF[6] = kk[6];
        }
    }
    __syncthreads();

    // ---- compact + write kept rows (mask broadcast from LDS) ----
    if (tid < TOPK) {
        const int wsel = tid >> 5, bsel = tid & 31;
        if ((kwF[wsel] >> bsel) & 1u) {
            int pos = 0;
#pragma unroll
            for (int w = 0; w < KW; w++) {
                unsigned kw_ = kwF[w];
                if (w < wsel) pos += __popc(kw_);
                else if (w == wsel) pos += __popc(kw_ & ((bsel == 0) ? 0u : (0xFFFFFFFFu >> (32 - bsel))));
            }
            float4 jb = bbox[tid];
            float* o = out + (((long)b * 2 + 1) * TOPK + pos) * 5;
            o[0] = bsc_s[tid];
            o[1] = jb.x;
            o[2] = jb.y;
            o[3] = jb.z;
            o[4] = jb.w;
        }
    }
}

extern "C" void kernel_launch(void* const* d_in, const int* in_sizes, int n_in,
                              void* d_out, int out_size, void* d_ws, size_t ws_size,
                              hipStream_t stream) {
    const float* loc   = (const float*)d_in[0];   // [64, 72192, 4]
    const float* conf  = (const float*)d_in[1];   // [64*72192, 2]
    const float* prior = (const float*)d_in[2];   // [72192, 4]
    float* out = (float*)d_out;                   // [64, 2, 200, 5]

    // ws layout (all regions fully written every launch -> no memset needed)
    char* w = (char*)d_ws;
    unsigned short* shist = (unsigned short*)w;            // 64*32*256 u16 = 1,048,576
    unsigned* scnt = (unsigned*)(w + 1048576);             // 64*32 u32     =     8,192
    u64* cand      = (u64*)(w + 1056768);                  // 64*32*64 u64  = 1,048,576

    histcollect_kernel<<<dim3(SLICES, BATCH), 256, 0, stream>>>(conf, shist, scnt, cand);
    fixup_kernel<<<BATCH, 256, 0, stream>>>(conf, shist, scnt, cand);
    nms_kernel<<<BATCH, NMS_NTH, 0, stream>>>(loc, prior, scnt, cand, out);
}

// Round 9
// 38.746 us; speedup vs baseline: 2.5174x; 1.0698x over previous
//
#include <hip/hip_runtime.h>
#include <math.h>

#pragma clang fp contract(off)

#define NUM_PRIORS 72192
#define BATCH      64
#define TOPK       200
#define CONF_TH    0.01f
#define NMS_TH     0.45f
#define NBINS      256
#define SLICES     32
#define ROWS       (NUM_PRIORS / SLICES)   // 2256
#define Q4         (ROWS / 2)              // 1128 float4 per slice
#define QB         (NUM_PRIORS / 2)        // 36096 float4 per batch
#define CAPS       64                      // candidate slots per slice segment
#define CAP        1024                    // max merged candidates per batch
#define KW         7                       // keep-mask words, ceil(200/32)
#define NMS_NTH    1024                    // nms block size (16 waves)
#define B255       0.99609375f             // 255/256: s >= B255 <=> bin_of(s) == 255

typedef unsigned long long u64;

// ---- binning: monotonic map score -> bin (cold path only) ----
__device__ __forceinline__ int bin_of(float s) {
    int b = (int)(s * 256.0f);
    return b > 255 ? 255 : b;
}

// ---- kernel 1: collect bin-255 candidates, store TRUE per-slice counts ----
__global__ __launch_bounds__(256) void collect255_kernel(const float* __restrict__ conf,
                                                         unsigned* __restrict__ scnt,
                                                         u64* __restrict__ cand) {
    __shared__ unsigned lcnt;
    const int b = blockIdx.y, slice = blockIdx.x, tid = threadIdx.x;
    if (tid == 0) lcnt = 0;
    __syncthreads();
    const float4* c4 = (const float4*)conf;
    const long base4 = (long)b * QB + (long)slice * Q4;
    const int prow0 = slice * ROWS;
    u64* seg = cand + ((long)b * SLICES + slice) * CAPS;

    float4 v0 = c4[base4 + tid];
    float4 v1 = c4[base4 + tid + 256];
    float4 v2 = c4[base4 + tid + 512];
    float4 v3 = c4[base4 + tid + 768];

#define P255(sv, pidx)                                                          \
    do {                                                                        \
        float s_ = (sv);                                                        \
        if (s_ >= B255) {                                                       \
            unsigned pos = atomicAdd(&lcnt, 1u);                                \
            if (pos < CAPS)                                                     \
                seg[pos] = ((u64)__float_as_uint(s_) << 32) |                   \
                           (u64)(0xFFFFFFFFu - (unsigned)(pidx));               \
        }                                                                       \
    } while (0)

    P255(v0.y, prow0 + 2 * tid);
    P255(v0.w, prow0 + 2 * tid + 1);
    P255(v1.y, prow0 + 2 * (tid + 256));
    P255(v1.w, prow0 + 2 * (tid + 256) + 1);
    P255(v2.y, prow0 + 2 * (tid + 512));
    P255(v2.w, prow0 + 2 * (tid + 512) + 1);
    P255(v3.y, prow0 + 2 * (tid + 768));
    P255(v3.w, prow0 + 2 * (tid + 768) + 1);
    if (tid < Q4 - 1024) {
        float4 vt = c4[base4 + tid + 1024];
        P255(vt.y, prow0 + 2 * (tid + 1024));
        P255(vt.w, prow0 + 2 * (tid + 1024) + 1);
    }
#undef P255
    __syncthreads();
    if (tid == 0) scnt[b * SLICES + slice] = lcnt;   // TRUE count (uncapped)
}

// ------- kernel 2: validity check (+exact cold fallback), merge, rank, decode,
//         row-mask NMS, wave0 greedy, compact -------
__global__ __launch_bounds__(NMS_NTH) void nms_kernel(const float* __restrict__ loc,
                           const float* __restrict__ prior,
                           const float* __restrict__ conf,
                           const unsigned* __restrict__ scnt,
                           u64* __restrict__ cand,
                           float* __restrict__ out) {
    __shared__ u64 keys[CAP];
    __shared__ float4 bbox[224];            // padded so batched loads never go OOB
    __shared__ float bsc_s[TOPK];
    __shared__ unsigned invR[TOPK][8];      // row i: ~suppression bits over j (pad=~0)
    __shared__ unsigned kw0[8];
    __shared__ unsigned kwF[KW];            // final keep mask (published by wave 0)
    __shared__ int soff[SLICES + 1];
    __shared__ int scl[SLICES];
    __shared__ unsigned histc[NBINS];       // cold path only
    __shared__ unsigned lcnt32[SLICES];     // cold path only
    __shared__ int TshC, needfix;
    const int b = blockIdx.x, tid = threadIdx.x;

    // ---- phase A: wave0 scan + validity; others zero out/kw0 ----
    if (tid < 64) {
        int s = tid;
        unsigned cs = (s < SLICES) ? scnt[b * SLICES + s] : 0u;
        int c = (cs < CAPS) ? (int)cs : CAPS;
        int v = c;
#pragma unroll
        for (int d = 1; d < 32; d <<= 1) {
            int o = __shfl_up(v, d);
            if ((int)tid >= d) v += o;
        }
        unsigned tot = cs;
#pragma unroll
        for (int d = 32; d >= 1; d >>= 1) tot += __shfl_xor(tot, d);
        u64 ovb = __ballot(cs > CAPS);
        if (s < SLICES) {
            int P = v - c;
            int off = P > CAP ? CAP : P;
            int rem = CAP - off;
            int cl = c < rem ? c : rem;
            soff[s] = off;
            scl[s] = cl;
            if (s == SLICES - 1) soff[SLICES] = (P + c > CAP) ? CAP : (P + c);
        }
        if (tid == 0) {
            needfix = (tot < TOPK) || (ovb != 0ull);
            TshC = 0;
        }
    }
    {
        float* ob = out + (long)b * 2 * TOPK * 5;
        for (int i = tid; i < 2 * TOPK * 5; i += NMS_NTH) ob[i] = 0.f;
    }
    if (tid < 8) kw0[tid] = 0u;
    __syncthreads();

    // ---- cold exact fallback (block-uniform; never taken on well-behaved data) ----
    if (needfix) {
        const float4* c4 = (const float4*)conf;
        for (int i = tid; i < NBINS; i += NMS_NTH) histc[i] = 0u;
        __syncthreads();
        for (int q = tid; q < QB; q += NMS_NTH) {
            float4 v = c4[(long)b * QB + q];
            if (v.y > CONF_TH) atomicAdd(&histc[bin_of(v.y)], 1u);
            if (v.w > CONF_TH) atomicAdd(&histc[bin_of(v.w)], 1u);
        }
        __syncthreads();
        for (int off = 1; off < NBINS; off <<= 1) {
            unsigned vv = 0u;
            if (tid < NBINS && tid + off < NBINS) vv = histc[tid + off];
            __syncthreads();
            if (tid < NBINS) histc[tid] += vv;
            __syncthreads();
        }
        if (tid < NBINS) {
            unsigned s0 = histc[tid];
            unsigned sn = (tid + 1 < NBINS) ? histc[tid + 1] : 0u;
            if (s0 >= TOPK && (tid == NBINS - 1 || sn < TOPK)) TshC = tid;
        }
        if (tid < SLICES) lcnt32[tid] = 0u;
        __syncthreads();
        const int T = TshC;
        for (int q = tid; q < QB; q += NMS_NTH) {
            float4 v = c4[(long)b * QB + q];
            int sl = q / Q4;
            u64* seg = cand + ((long)b * SLICES + sl) * CAPS;
            if (v.y > CONF_TH && bin_of(v.y) >= T) {
                unsigned pos = atomicAdd(&lcnt32[sl], 1u);
                if (pos < CAPS)
                    seg[pos] = ((u64)__float_as_uint(v.y) << 32) |
                               (u64)(0xFFFFFFFFu - (unsigned)(2 * q));
            }
            if (v.w > CONF_TH && bin_of(v.w) >= T) {
                unsigned pos = atomicAdd(&lcnt32[sl], 1u);
                if (pos < CAPS)
                    seg[pos] = ((u64)__float_as_uint(v.w) << 32) |
                               (u64)(0xFFFFFFFFu - (unsigned)(2 * q + 1));
            }
        }
        __syncthreads();
        if (tid < 64) {
            int s = tid;
            unsigned cs = (s < SLICES) ? lcnt32[s] : 0u;
            int c = (cs < CAPS) ? (int)cs : CAPS;
            int v = c;
#pragma unroll
            for (int d = 1; d < 32; d <<= 1) {
                int o = __shfl_up(v, d);
                if ((int)tid >= d) v += o;
            }
            if (s < SLICES) {
                int P = v - c;
                int off = P > CAP ? CAP : P;
                int rem = CAP - off;
                int cl = c < rem ? c : rem;
                soff[s] = off;
                scl[s] = cl;
                if (s == SLICES - 1) soff[SLICES] = (P + c > CAP) ? CAP : (P + c);
            }
        }
        __syncthreads();
    }

    // ---- gather keys into LDS ----
    const int n = soff[SLICES];
    const int nn = (n + 15) & ~15;
    for (int pos = tid; pos < SLICES * CAPS; pos += NMS_NTH) {
        int s = pos >> 6, idx = pos & 63;
        if (idx < scl[s])
            keys[soff[s] + idx] = cand[((long)b * SLICES + s) * CAPS + idx];
    }
    for (int i = n + tid; i < nn; i += NMS_NTH) keys[i] = 0ull;   // zero pad
    __syncthreads();

    // ---- rank (exact top_k order: keys unique); only waves holding candidates run ----
    u64 kc = (tid < n) ? keys[tid] : 0ull;
    int rk = 0;
    if ((int)(tid & ~63u) < n) {                  // wave-uniform guard
        for (int k = 0; k < nn; k += 16) {
            u64 kb[16];
#pragma unroll
            for (int j = 0; j < 16; j++) kb[j] = keys[k + j];
#pragma unroll
            for (int j = 0; j < 16; j++) rk += (kb[j] > kc) ? 1 : 0;
        }
    }
    // ---- fused decode of winners (identical float expressions to prior rounds) ----
    if (tid < n && rk < TOPK) {
        u64 key = kc;
        float sc = __uint_as_float((unsigned)(key >> 32));
        unsigned p = 0xFFFFFFFFu - (unsigned)(key & 0xFFFFFFFFull);
        float4 l4 = ((const float4*)loc)[(long)b * NUM_PRIORS + p];
        float4 p4 = ((const float4*)prior)[p];
        float cx = p4.x + (l4.x * 0.1f) * p4.z;
        float cy = p4.y + (l4.y * 0.1f) * p4.w;
        float w_ = p4.z * (float)exp((double)(l4.z * 0.2f));
        float h_ = p4.w * (float)exp((double)(l4.w * 0.2f));
        float x1 = cx - w_ * 0.5f, y1 = cy - h_ * 0.5f;
        float x2 = cx + w_ * 0.5f, y2 = cy + h_ * 0.5f;
        bsc_s[rk] = sc;
        bbox[rk] = make_float4(x1, y1, x2, y2);
        atomicOr(&kw0[rk >> 5], 1u << (rk & 31));
    }
    __syncthreads();

    // ---- build inverted row-major suppression mask, 4-way split + batched loads ----
    // thread 256*q + i owns row i, words {q, q+4} (q==3: word 3 only)
    {
        const int q = tid >> 8, i = tid & 255;
        if (i < TOPK) {
            const float4 ib = bbox[i];
            const float iar = (ib.z - ib.x) * (ib.w - ib.y);   // same expr as reference
#pragma unroll
            for (int wi = 0; wi < 2; wi++) {
                if (wi == 1 && q == 3) break;
                const int w = (wi == 0) ? q : q + 4;
                const int jbase = w * 32;
                unsigned inv = 0xFFFFFFFFu;
#pragma unroll
                for (int g = 0; g < 32; g += 8) {
                    float4 J[8];
#pragma unroll
                    for (int r = 0; r < 8; r++) J[r] = bbox[jbase + g + r];  // broadcast, batched
#pragma unroll
                    for (int r = 0; r < 8; r++) {
                        const int j = jbase + g + r;
                        if (j > i && j < TOPK) {
                            float4 jb = J[r];
                            float jar = (jb.z - jb.x) * (jb.w - jb.y);
                            float ltx = fmaxf(ib.x, jb.x);
                            float lty = fmaxf(ib.y, jb.y);
                            float rbx = fminf(ib.z, jb.z);
                            float rby = fminf(ib.w, jb.w);
                            float wx = fmaxf(rbx - ltx, 0.0f);
                            float wy = fmaxf(rby - lty, 0.0f);
                            float inter = wx * wy;
                            float uni = (iar + jar) - inter;
                            float iou = inter / fmaxf(uni, 1e-12f);
                            if (iou > NMS_TH) inv &= ~(1u << (g + r));
                        }
                    }
                }
                invR[i][w] = inv;
            }
        }
    }
    __syncthreads();

    // ---- greedy resolve: wave 0 only, register keep-mask, 8 rows per group ----
    if (tid < 64) {
        unsigned kk[KW];
#pragma unroll
        for (int w = 0; w < KW; w++) kk[w] = kw0[w];
#pragma unroll
        for (int g = 0; g < TOPK; g += 8) {
            uint4 A[8], C[8];
#pragma unroll
            for (int r = 0; r < 8; r++) {
                A[r] = *(const uint4*)&invR[g + r][0];
                C[r] = *(const uint4*)&invR[g + r][4];
            }
#pragma unroll
            for (int r = 0; r < 8; r++) {
                const int i = g + r;                     // compile-time
                if ((kk[i >> 5] >> (i & 31)) & 1u) {
                    kk[0] &= A[r].x; kk[1] &= A[r].y; kk[2] &= A[r].z; kk[3] &= A[r].w;
                    kk[4] &= C[r].x; kk[5] &= C[r].y; kk[6] &= C[r].z;
                }
            }
        }
        if (tid == 0) {                                  // static indices (no scratch)
            kwF[0] = kk[0]; kwF[1] = kk[1]; kwF[2] = kk[2]; kwF[3] = kk[3];
            kwF[4] = kk[4]; kwF[5] = kk[5]; kwF[6] = kk[6];
        }
    }
    __syncthreads();

    // ---- compact + write kept rows (mask broadcast from LDS) ----
    if (tid < TOPK) {
        const int wsel = tid >> 5, bsel = tid & 31;
        if ((kwF[wsel] >> bsel) & 1u) {
            int pos = 0;
#pragma unroll
            for (int w = 0; w < KW; w++) {
                unsigned kw_ = kwF[w];
                if (w < wsel) pos += __popc(kw_);
                else if (w == wsel) pos += __popc(kw_ & ((bsel == 0) ? 0u : (0xFFFFFFFFu >> (32 - bsel))));
            }
            float4 jb = bbox[tid];
            float* o = out + (((long)b * 2 + 1) * TOPK + pos) * 5;
            o[0] = bsc_s[tid];
            o[1] = jb.x;
            o[2] = jb.y;
            o[3] = jb.z;
            o[4] = jb.w;
        }
    }
}

extern "C" void kernel_launch(void* const* d_in, const int* in_sizes, int n_in,
                              void* d_out, int out_size, void* d_ws, size_t ws_size,
                              hipStream_t stream) {
    const float* loc   = (const float*)d_in[0];   // [64, 72192, 4]
    const float* conf  = (const float*)d_in[1];   // [64*72192, 2]
    const float* prior = (const float*)d_in[2];   // [72192, 4]
    float* out = (float*)d_out;                   // [64, 2, 200, 5]

    // ws layout (all regions fully written every launch -> no memset needed)
    char* w = (char*)d_ws;
    unsigned* scnt = (unsigned*)w;                         // 64*32 u32    = 8,192
    u64* cand      = (u64*)(w + 8192);                     // 64*32*64 u64 = 1,048,576

    collect255_kernel<<<dim3(SLICES, BATCH), 256, 0, stream>>>(conf, scnt, cand);
    nms_kernel<<<BATCH, NMS_NTH, 0, stream>>>(loc, prior, conf, scnt, cand, out);
}